// Round 7
// baseline (34.800 us; speedup 1.0000x reference)
//
#include <hip/hip_runtime.h>

// Problem constants
#define BB 256
#define GG 16
#define LL 16
#define CC 8192
#define KK 8
// GAMMA_NEG=4, GAMMA_POS=1, CLIP=0.05, EPS=1e-8

typedef float f32x4 __attribute__((ext_vector_type(4)));

__device__ __forceinline__ float sigmoid_fast(float x) {
    float u = __expf(-x);                        // v_exp_f32
    return __builtin_amdgcn_rcpf(1.0f + u);      // v_rcp_f32
}

// target==0: t = max(s-0.05,0);  f_neg = -log(1-t) * t^4   (1-t >= 0.05 > EPS)
__device__ __forceinline__ float f_neg(float x) {
    float s  = sigmoid_fast(x);
    float t  = fmaxf(s - 0.05f, 0.0f);
    float l  = __logf(1.0f - t);
    float t2 = t * t;
    return -l * (t2 * t2);
}

// target==1: f_pos = -log(max(s,eps)) * (1-s)
__device__ __forceinline__ float f_pos(float x) {
    float s = sigmoid_fast(x);
    float l = __logf(fmaxf(s, 1e-8f));
    return -l * (1.0f - s);
}

// ---------------------------------------------------------------------------
// 2048 blocks x 256 threads = exactly 8 blocks/CU, fully resident (m13-shaped
// stream). Block blk owns the contiguous 64 KB span of rows {2blk, 2blk+1}:
//  - depth-4 named-register software pipeline over 16 f32x4 rounds
//    (load i+4 while computing i; all indices static)
//  - wave w (w=0,1) does row (2blk+w)'s side work: cnt + <=8 scattered
//    pos-correction gathers, issued BEFORE the stream to hide their latency
//  partial[row] = cnt * rowsum_neg + corrsum   (plain store; the kernel
//  boundary is the sync -- R4/R5: fences and same-line atomics are disasters)
// ---------------------------------------------------------------------------
__global__ __launch_bounds__(256) void main_kernel(
    const float* __restrict__ logits, const int* __restrict__ param,
    const int* __restrict__ label, const int* __restrict__ num,
    float* __restrict__ partial) {
    const int blk  = blockIdx.x;
    const int row0 = blk << 1;                   // first of two rows
    const int tid  = threadIdx.x;
    const int wid  = tid >> 6;
    const int lane = tid & 63;

    // ---- side work: wave w handles row row0+w ----
    int   match   = 0;
    int   corr_on = 0;
    float xg      = 0.0f;
    if (wid < 2) {
        const int row = row0 + wid;
        const int g   = row >> 8;
        const int b   = row & (BB - 1);
        if (lane < LL) {                         // cnt contribution
            int pv = param[b * LL + lane];
            match = (pv >= 0) && (min(pv, GG - 1) == g);
        }
        const int t  = b * LL + g;               // this wave's (b,l) pair
        const int pv = param[t];                 // broadcast load
        const int n  = min(num[t], KK);
        int myc = 0;
        if (lane < KK) myc = label[t * KK + lane];
        bool dup = false;                        // min(label_bit,1) clamp
#pragma unroll
        for (int j = 0; j < KK - 1; ++j) {
            int cj = __shfl(myc, j, 64);
            dup = dup || ((j < lane) && (cj == myc));
        }
        corr_on = (pv >= 0) && (lane < n) && !dup;
        if (corr_on) {
            const int p = min(pv, GG - 1);
            xg = logits[((size_t)p * BB + b) * CC + myc];   // scattered gather
        }
    }

    // ---- stream 64 KB: 16 rounds, depth-4 pipeline, static indices ----
    const f32x4* base = reinterpret_cast<const f32x4*>(logits)
                        + (size_t)row0 * (CC / 4);
    f32x4 v0 = base[tid];
    f32x4 v1 = base[tid + 256];
    f32x4 v2 = base[tid + 512];
    f32x4 v3 = base[tid + 768];
    float accA = 0.0f, accB = 0.0f;              // row A = iters 0..7, B = 8..15
#define STEP(i, VV)                                                          \
    {                                                                        \
        f32x4 cur = VV;                                                      \
        if ((i) + 4 < 16) VV = base[tid + ((i) + 4) * 256];                  \
        float r = (f_neg(cur.x) + f_neg(cur.y)) + (f_neg(cur.z) + f_neg(cur.w)); \
        if ((i) < 8) accA += r; else accB += r;                              \
    }
    STEP(0, v0)  STEP(1, v1)  STEP(2, v2)  STEP(3, v3)
    STEP(4, v0)  STEP(5, v1)  STEP(6, v2)  STEP(7, v3)
    STEP(8, v0)  STEP(9, v1)  STEP(10, v2) STEP(11, v3)
    STEP(12, v0) STEP(13, v1) STEP(14, v2) STEP(15, v3)
#undef STEP

#pragma unroll
    for (int off = 32; off > 0; off >>= 1) {
        accA += __shfl_down(accA, off, 64);
        accB += __shfl_down(accB, off, 64);
    }
    __shared__ float smA[4], smB[4];
    if (lane == 0) { smA[wid] = accA; smB[wid] = accB; }
    __syncthreads();

    if (wid < 2) {
        float corr = corr_on ? (f_pos(xg) - f_neg(xg)) : 0.0f;
        int   cnt  = match;
#pragma unroll
        for (int off = 32; off > 0; off >>= 1) {
            corr += __shfl_down(corr, off, 64);
            cnt  += __shfl_down(cnt, off, 64);
        }
        if (lane == 0) {
            const float* sp = (wid == 0) ? smA : smB;
            float rowsum = (sp[0] + sp[1]) + (sp[2] + sp[3]);
            partial[row0 + wid] = (float)cnt * rowsum + corr;
        }
    }
}

// ---------------------------------------------------------------------------
// Final: reduce 4096 partials -> mean over B. Fixed-order tree: deterministic.
// ---------------------------------------------------------------------------
__global__ __launch_bounds__(1024) void reduce_kernel(
    const float* __restrict__ partial, float* __restrict__ out) {
    const f32x4 v = reinterpret_cast<const f32x4*>(partial)[threadIdx.x];
    float s = (v.x + v.y) + (v.z + v.w);
#pragma unroll
    for (int off = 32; off > 0; off >>= 1) s += __shfl_down(s, off, 64);
    __shared__ float sm[16];
    if ((threadIdx.x & 63) == 0) sm[threadIdx.x >> 6] = s;
    __syncthreads();
    if (threadIdx.x < 64) {
        float v2 = (threadIdx.x < 16) ? sm[threadIdx.x] : 0.0f;
#pragma unroll
        for (int off = 8; off > 0; off >>= 1) v2 += __shfl_down(v2, off, 64);
        if (threadIdx.x == 0) out[0] = v2 * (1.0f / (float)BB);
    }
}

extern "C" void kernel_launch(void* const* d_in, const int* in_sizes, int n_in,
                              void* d_out, int out_size, void* d_ws, size_t ws_size,
                              hipStream_t stream) {
    const float* logits = (const float*)d_in[0];   // (G, B, C) f32
    const int*   param  = (const int*)d_in[1];     // (B, L)
    const int*   label  = (const int*)d_in[2];     // (B, L, K)
    const int*   num    = (const int*)d_in[3];     // (B, L)
    float* out = (float*)d_out;
    float* partial = (float*)d_ws;                 // 4096 floats

    main_kernel<<<(GG * BB) / 2, 256, 0, stream>>>(logits, param, label, num, partial);
    reduce_kernel<<<1, 1024, 0, stream>>>(partial, out);
}